// Round 17
// baseline (870.914 us; speedup 1.0000x reference)
//
#include <hip/hip_runtime.h>

#define D 256
#define BN_EPS 1e-5f

typedef __attribute__((ext_vector_type(8))) short short8;
typedef __attribute__((ext_vector_type(4))) short short4v;
typedef __attribute__((ext_vector_type(4))) float f32x4;
typedef __attribute__((ext_vector_type(2))) float f32x2;

__device__ __forceinline__ float b2f(ushort u) {
    union { unsigned u; float f; } c; c.u = ((unsigned)u) << 16; return c.f;
}
__device__ __forceinline__ ushort f2b(float f) {
    union { float f; unsigned u; } c; c.f = f;
    return (ushort)((c.u + 0x7fffu + ((c.u >> 16) & 1u)) >> 16);
}

typedef __attribute__((address_space(1))) const void gv_t;
typedef __attribute__((address_space(3))) void lv_t;
__device__ __forceinline__ void gld16(const void* g, void* l) {
    __builtin_amdgcn_global_load_lds((gv_t*)g, (lv_t*)l, 16, 0, 0);
}

// pack 8 floats -> 8 fp8 e4m3 (two dwords)
__device__ __forceinline__ uint2 pk_fp8x8(const float* r) {
    unsigned w0 = 0, w1 = 0;
    w0 = __builtin_amdgcn_cvt_pk_fp8_f32(r[0], r[1], w0, false);
    w0 = __builtin_amdgcn_cvt_pk_fp8_f32(r[2], r[3], w0, true);
    w1 = __builtin_amdgcn_cvt_pk_fp8_f32(r[4], r[5], w1, false);
    w1 = __builtin_amdgcn_cvt_pk_fp8_f32(r[6], r[7], w1, true);
    return make_uint2(w0, w1);
}

// ---------------- degree via LDS multi-range histogram ----------------

#define HB 64   // blocks per combo

__global__ __launch_bounds__(256) void hist_kernel(const int* __restrict__ src,
                                                   const int* __restrict__ dst,
                                                   unsigned* __restrict__ P, int E) {
    __shared__ unsigned lhist[16384];
    int combo = blockIdx.y;
    const int* arr = (combo >> 2) ? dst : src;
    unsigned base = (unsigned)(combo & 3) << 15;
    for (int j = threadIdx.x; j < 16384; j += 256) lhist[j] = 0;
    __syncthreads();
    int i0 = (blockIdx.x * 256 + threadIdx.x) * 4;
    int stride = HB * 256 * 4;
    for (int i = i0; i < E; i += stride) {
        if (i + 3 < E) {
            int4 v = *(const int4*)(arr + i);
            unsigned r0 = (unsigned)v.x - base;
            unsigned r1 = (unsigned)v.y - base;
            unsigned r2 = (unsigned)v.z - base;
            unsigned r3 = (unsigned)v.w - base;
            if (r0 < 32768u) atomicAdd(&lhist[r0 >> 1], 1u << ((r0 & 1) << 4));
            if (r1 < 32768u) atomicAdd(&lhist[r1 >> 1], 1u << ((r1 & 1) << 4));
            if (r2 < 32768u) atomicAdd(&lhist[r2 >> 1], 1u << ((r2 & 1) << 4));
            if (r3 < 32768u) atomicAdd(&lhist[r3 >> 1], 1u << ((r3 & 1) << 4));
        } else {
            for (int j = i; j < E; j++) {
                unsigned r = (unsigned)arr[j] - base;
                if (r < 32768u) atomicAdd(&lhist[r >> 1], 1u << ((r & 1) << 4));
            }
        }
    }
    __syncthreads();
    unsigned* dstp = P + ((size_t)(combo * HB + blockIdx.x) << 14);
    for (int j = threadIdx.x; j < 16384; j += 256) dstp[j] = lhist[j];
}

__global__ void histreduce_kernel(const unsigned* __restrict__ P,
                                  int* __restrict__ cntO, int* __restrict__ cntI, int N) {
    int g = blockIdx.x * 256 + threadIdx.x;       // 0 .. 131071
    int array = g >> 16;
    int p = g & 65535;
    int range = p >> 14;
    int j = p & 16383;
    const unsigned* Pp = P + ((size_t)((array * 4 + range) * HB) << 14) + j;
    unsigned s = 0;
#pragma unroll 8
    for (int b = 0; b < HB; b++) s += Pp[(size_t)b << 14];
    int bin = (range << 15) + 2 * j;
    int* cnt = array ? cntI : cntO;
    if (bin < N)     cnt[bin]     = (int)(s & 0xFFFFu);
    if (bin + 1 < N) cnt[bin + 1] = (int)(s >> 16);
}

__global__ void invsqrt_kernel(const int* __restrict__ cntO, const int* __restrict__ cntI,
                               float* __restrict__ invO, float* __restrict__ invOI,
                               float* __restrict__ sqrtO, int N) {
    int i = blockIdx.x * blockDim.x + threadIdx.x;
    if (i < N) {
        float dO = (float)max(cntO[i], 1);
        float io = rsqrtf(dO);
        invO[i] = io;
        sqrtO[i] = sqrtf(dO);
        invOI[i] = io * rsqrtf((float)max(cntI[i], 1));
    }
}

// hierarchical exclusive scan over PADDED counts ((deg+7)&~7)
__global__ void scan1_kernel(const int* __restrict__ cnt, int* __restrict__ off,
                             int* __restrict__ bsum, int n) {
    __shared__ int s[256];
    int t = threadIdx.x;
    int i0 = blockIdx.x * 1024 + t * 4;
    int v0 = (i0 < n) ? ((cnt[i0] + 7) & ~7) : 0;
    int v1 = (i0 + 1 < n) ? ((cnt[i0 + 1] + 7) & ~7) : 0;
    int v2 = (i0 + 2 < n) ? ((cnt[i0 + 2] + 7) & ~7) : 0;
    int v3 = (i0 + 3 < n) ? ((cnt[i0 + 3] + 7) & ~7) : 0;
    int tsum = v0 + v1 + v2 + v3;
    s[t] = tsum;
    __syncthreads();
    for (int d = 1; d < 256; d <<= 1) {
        int x = (t >= d) ? s[t - d] : 0;
        __syncthreads();
        s[t] += x;
        __syncthreads();
    }
    int excl = s[t] - tsum;
    if (i0 < n)     off[i0]     = excl;
    if (i0 + 1 < n) off[i0 + 1] = excl + v0;
    if (i0 + 2 < n) off[i0 + 2] = excl + v0 + v1;
    if (i0 + 3 < n) off[i0 + 3] = excl + v0 + v1 + v2;
    if (t == 255) bsum[blockIdx.x] = s[255];
}

__global__ void scan2_kernel(int* __restrict__ bsum, int nb) {
    __shared__ int s[256];
    int t = threadIdx.x;
    int v = (t < nb) ? bsum[t] : 0;
    s[t] = v;
    __syncthreads();
    for (int d = 1; d < 256; d <<= 1) {
        int x = (t >= d) ? s[t - d] : 0;
        __syncthreads();
        s[t] += x;
        __syncthreads();
    }
    if (t < nb) bsum[t] = s[t] - v;   // exclusive
    if (t == nb - 1) bsum[1023] = s[t];  // padded grand total
}

__global__ void scan3_kernel(int* __restrict__ off, const int* __restrict__ bsum,
                             int* __restrict__ bucketCur, int n) {
    int i = blockIdx.x * blockDim.x + threadIdx.x;
    if (i < n) {
        int v = off[i] + bsum[i >> 10];
        off[i] = v;
        if ((i & 255) == 0) bucketCur[i >> 8] = v;   // bucket cursor init fused
    } else if (i == n) {
        off[n] = bsum[1023];
    }
}

// ---------------- bucketed edge sort ----------------

#define NBKMAX 512

__global__ __launch_bounds__(256) void partA_kernel(const int* __restrict__ src,
                                                    const int* __restrict__ dst,
                                                    int* __restrict__ bucketCur,
                                                    unsigned* __restrict__ pairs,
                                                    int E, int NBK) {
    __shared__ int cnt[NBKMAX];
    __shared__ int base_s[NBKMAX];
    for (int j = threadIdx.x; j < NBK; j += 256) cnt[j] = 0;
    __syncthreads();
    for (int i = blockIdx.x * 256 + threadIdx.x; i < E; i += gridDim.x * 256)
        atomicAdd(&cnt[((unsigned)dst[i]) >> 8], 1);
    __syncthreads();
    for (int j = threadIdx.x; j < NBK; j += 256) {
        base_s[j] = atomicAdd(&bucketCur[j], cnt[j]);
        cnt[j] = 0;
    }
    __syncthreads();
    for (int i = blockIdx.x * 256 + threadIdx.x; i < E; i += gridDim.x * 256) {
        unsigned d = (unsigned)dst[i];
        unsigned b = d >> 8;
        int pos = base_s[b] + atomicAdd(&cnt[b], 1);
        pairs[pos] = ((unsigned)src[i] << 8) | (d & 255u);
    }
}

#define BCAP 14336

__global__ __launch_bounds__(256) void partB_kernel(const unsigned* __restrict__ pairs,
                                                    const int* __restrict__ off,
                                                    const int* __restrict__ bucketCur,
                                                    int* __restrict__ srcS, int N) {
    __shared__ int curL[256];
    __shared__ int stage[BCAP];
    int b = blockIdx.x;
    int n0 = b << 8;
    int n1 = min(n0 + 256, N);
    int base = off[n0];
    int len = off[n1] - base;
    if (len > BCAP) len = BCAP;
    for (int j = threadIdx.x; j < len; j += 256) stage[j] = N;
    int nn = n1 - n0;
    for (int i = threadIdx.x; i < nn; i += 256) curL[i] = off[n0 + i] - base;
    __syncthreads();
    int cntB = bucketCur[b] - base;
    for (int j = threadIdx.x; j < cntB; j += 256) {
        unsigned p = pairs[base + j];
        int pos = atomicAdd(&curL[p & 255u], 1);
        if (pos < BCAP) stage[pos] = (int)(p >> 8);
    }
    __syncthreads();
    for (int j4 = threadIdx.x; j4 * 4 < len; j4 += 256)
        *(int4*)(srcS + base + j4 * 4) = *(const int4*)(stage + j4 * 4);
}

// zero the dummy row N of X (bf16) and X8 (fp8, 64 dwords)
__global__ void init_pad_kernel(ushort* __restrict__ X, unsigned* __restrict__ X8, int N) {
    int t = threadIdx.x;
    X[(size_t)N * D + t] = 0;
    if (t < 64) X8[(size_t)N * 64 + t] = 0;
}

// ---------------- prep: Wt[l][n][k] = bf16 of [W; Wl+I]^T, bcat = b+bl ----------------

__global__ void prep_w_kernel(const float* __restrict__ W, const float* __restrict__ Wl,
                              const float* __restrict__ b, const float* __restrict__ bl,
                              ushort* __restrict__ Wt, float* __restrict__ bcat, int L) {
    int idx = blockIdx.x * blockDim.x + threadIdx.x;
    int k = idx & 511;
    int n = (idx >> 9) & 255;
    int l = idx >> 17;
    if (l >= L) return;
    float v;
    if (k < 256) {
        v = W[(size_t)l * 65536 + k * 256 + n];
    } else {
        v = Wl[(size_t)l * 65536 + (k - 256) * 256 + n];
        if (k - 256 == n) v += 1.0f;      // residual folded: h@Wl + h = h@(Wl+I)
    }
    Wt[idx] = f2b(v);
    if (k == 0) bcat[l * 256 + n] = b[l * 256 + n] + bl[l * 256 + n];
}

// x -> hs0 = x * invO[row]: bf16 copy (GEMM) + fp8 copy (gather)
__global__ void x2b_kernel(const float* __restrict__ x, const float* __restrict__ invO,
                           ushort* __restrict__ hs, unsigned* __restrict__ hs8, long n8) {
    long i8 = (long)blockIdx.x * blockDim.x + threadIdx.x;
    if (i8 >= n8) return;
    long row = i8 >> 5;
    float sc = invO[row];
    float4 a = ((const float4*)x)[i8 * 2];
    float4 b = ((const float4*)x)[i8 * 2 + 1];
    float r[8] = { a.x * sc, a.y * sc, a.z * sc, a.w * sc,
                   b.x * sc, b.y * sc, b.z * sc, b.w * sc };
    ushort v[8];
#pragma unroll
    for (int j = 0; j < 8; j++) v[j] = f2b(r[j]);
    *(short8*)(hs + i8 * 8) = *(short8*)v;
    *(uint2*)(hs8 + i8 * 2) = pk_fp8x8(r);
}

// ---------------- fused aggregate + GEMM ----------------
// Block = 512 threads (8 waves), owns 64 output rows.
// Phase 1: each wave gathers 8 nodes (fp8, 8 edges in flight) into swizzled LDS A-tile.
// Phase 2: 64x256x512 MFMA GEMM; A[k<256] from LDS tile, A[k>=256]=hs staged, B staged.
// LDS 52 KB -> 3 blocks/CU = 24 waves/CU: gather TLP matches standalone aggregate,
// and blocks at different phases overlap fabric (gather) with MFMA (gemm).

#define ASTG 0        // 16384 shorts (32 KB): 64x256 bf16 A-tile, row-XOR swizzled
#define BST  16384    // 8192 shorts (16 KB): 256x32 B-tile
#define AHS  24576    // 2048 shorts (4 KB): 64x32 hs A-slice

__global__ __launch_bounds__(512, 6) void aggemm_kernel(
        const unsigned* __restrict__ X8, const ushort* __restrict__ hs,
        const float* __restrict__ invOI, const float* __restrict__ sqrtO,
        const int* __restrict__ off, const int* __restrict__ srcS,
        const ushort* __restrict__ Wt, const float* __restrict__ bcat,
        ushort* __restrict__ tmp, float* __restrict__ bnsum, float* __restrict__ bnsq,
        int M) {
    __shared__ short SH[26624];   // 53248 B

    int bm0 = blockIdx.x * 64;
    int tid = threadIdx.x;
    int wid = tid >> 6, lane = tid & 63;

    // ---- phase 1: gather 8 nodes per wave into Astage ----
    for (int r = 0; r < 8; r++) {
        int rr = wid * 8 + r;
        int node = bm0 + rr;
        f32x2 A01 = {0.f, 0.f}, A23 = {0.f, 0.f};
        float wi = 0.f;
        if (node < M) {
            int e0 = off[node], e1 = off[node + 1];
            for (int e = e0; e < e1; e += 8) {
                int4 c0 = *(const int4*)(srcS + e);
                int4 c1 = *(const int4*)(srcS + e + 4);
                unsigned g0 = X8[(size_t)c0.x * 64 + lane];
                unsigned g1 = X8[(size_t)c0.y * 64 + lane];
                unsigned g2 = X8[(size_t)c0.z * 64 + lane];
                unsigned g3 = X8[(size_t)c0.w * 64 + lane];
                unsigned g4 = X8[(size_t)c1.x * 64 + lane];
                unsigned g5 = X8[(size_t)c1.y * 64 + lane];
                unsigned g6 = X8[(size_t)c1.z * 64 + lane];
                unsigned g7 = X8[(size_t)c1.w * 64 + lane];
#pragma unroll
                for (int q = 0; q < 8; q++) {
                    unsigned g = (q == 0) ? g0 : (q == 1) ? g1 : (q == 2) ? g2 : (q == 3) ? g3
                               : (q == 4) ? g4 : (q == 5) ? g5 : (q == 6) ? g6 : g7;
                    A01 += __builtin_amdgcn_cvt_pk_f32_fp8(g, false);
                    A23 += __builtin_amdgcn_cvt_pk_f32_fp8(g, true);
                }
            }
            wi = invOI[node];
        }
        ushort o[4] = { f2b(A01[0] * wi), f2b(A01[1] * wi),
                        f2b(A23[0] * wi), f2b(A23[1] * wi) };
        unsigned byteoff = (unsigned)(rr * 512 + lane * 8) ^ ((unsigned)(rr & 7) << 4);
        *(short4v*)((char*)SH + byteoff) = *(short4v*)o;
    }
    __syncthreads();

    // ---- phase 2: 64x256 GEMM over K=512 ----
    int wr = wid >> 2, wc = wid & 3;          // wave grid 2 (rows) x 4 (cols)
    int lrow = lane & 15, lkh = lane >> 4;
    int srow = lane >> 2;
    int sseg = (lane & 3) ^ ((srow >> 1) & 3);

    f32x4 acc[2][4] = {};

#pragma unroll
    for (int k0 = 0; k0 < 512; k0 += 32) {
        {
            const ushort* gb = Wt + (size_t)(wid * 32 + srow) * 512 + k0 + sseg * 8;
            gld16(gb,            SH + BST + (wid * 32) * 32);
            gld16(gb + 16 * 512, SH + BST + (wid * 32 + 16) * 32);
            if (k0 >= 256 && wid < 4) {
                const ushort* ga = hs + (size_t)(bm0 + wid * 16 + srow) * 256
                                   + (k0 - 256) + sseg * 8;
                gld16(ga, SH + AHS + (wid * 16) * 32);
            }
        }
        __syncthreads();

        short8 a[2], bfr[4];
        if (k0 < 256) {
#pragma unroll
            for (int m = 0; m < 2; m++) {
                int ra = wr * 32 + m * 16 + lrow;
                unsigned bo = (unsigned)(ra * 512 + k0 * 2 + lkh * 16)
                              ^ ((unsigned)(ra & 7) << 4);
                a[m] = *(short8*)((char*)SH + bo);
            }
        } else {
#pragma unroll
            for (int m = 0; m < 2; m++) {
                int ra = wr * 32 + m * 16 + lrow;
                a[m] = *(short8*)&SH[AHS + ra * 32 + (lkh ^ ((ra >> 1) & 3)) * 8];
            }
        }
#pragma unroll
        for (int n = 0; n < 4; n++) {
            int rb = wc * 64 + n * 16 + lrow;
            bfr[n] = *(short8*)&SH[BST + rb * 32 + (lkh ^ ((rb >> 1) & 3)) * 8];
        }
#pragma unroll
        for (int m = 0; m < 2; m++)
#pragma unroll
            for (int n = 0; n < 4; n++)
                acc[m][n] = __builtin_amdgcn_mfma_f32_16x16x32_bf16(a[m], bfr[n], acc[m][n], 0, 0, 0);
        __syncthreads();
    }

    // register phase: scale rows, bias, bf16 values, column stats
    ushort outv[2][4][4];
#pragma unroll
    for (int n = 0; n < 4; n++) {
        int col = wc * 64 + n * 16 + lrow;
        float bc = bcat[col];
        float s_part = 0.f, q_part = 0.f;
#pragma unroll
        for (int m = 0; m < 2; m++) {
            int rbase = bm0 + wr * 32 + m * 16 + lkh * 4;
#pragma unroll
            for (int i = 0; i < 4; i++) {
                int row = rbase + i;
                float v = (row < M) ? (acc[m][n][i] * sqrtO[row] + bc) : 0.f;
                outv[m][n][i] = f2b(v);
                if (row < M) { s_part += v; q_part += v * v; }
            }
        }
        s_part += __shfl_xor(s_part, 16);
        s_part += __shfl_xor(s_part, 32);
        q_part += __shfl_xor(q_part, 16);
        q_part += __shfl_xor(q_part, 32);
        if (lkh == 0) {
            atomicAdd(&bnsum[col], s_part);
            atomicAdd(&bnsq[col], q_part);
        }
    }

    // coalesced store via LDS (reuse Astage region: 64x256 = 32 KB)
    __syncthreads();
#pragma unroll
    for (int m = 0; m < 2; m++)
#pragma unroll
        for (int n = 0; n < 4; n++)
#pragma unroll
            for (int i = 0; i < 4; i++)
                SH[(wr * 32 + m * 16 + lkh * 4 + i) * 256 + wc * 64 + n * 16 + lrow] =
                    (short)outv[m][n][i];
    __syncthreads();
#pragma unroll
    for (int p = 0; p < 2; p++) {
        int rl = p * 32 + (tid >> 4);
        int c0 = (tid & 15) * 16;
        int row = bm0 + rl;
        if (row < M) {
            *(short8*)(tmp + (size_t)row * 256 + c0)     = *(short8*)&SH[rl * 256 + c0];
            *(short8*)(tmp + (size_t)row * 256 + c0 + 8) = *(short8*)&SH[rl * 256 + c0 + 8];
        }
    }
}

// ---------------- BN finalize (+ re-zero stats for next layer) ----------------

__global__ void bnfin_kernel(float* __restrict__ bnsum, float* __restrict__ bnsq,
                             const float* __restrict__ gamma, const float* __restrict__ beta,
                             float2* __restrict__ bnab, float invM) {
    int c = threadIdx.x;
    float mean = bnsum[c] * invM;
    float var = bnsq[c] * invM - mean * mean;
    float a = gamma[c] * rsqrtf(var + BN_EPS);
    bnab[c] = make_float2(a, beta[c] - a * mean);
    bnsum[c] = 0.f;
    bnsq[c] = 0.f;
}

__global__ void bnrelu_kernel(const ushort* __restrict__ tmp, const float2* __restrict__ bnab,
                              const float* __restrict__ invO, ushort* __restrict__ Xout,
                              unsigned* __restrict__ X8out, float* __restrict__ out,
                              int M, int last) {
    long i8 = (long)blockIdx.x * blockDim.x + threadIdx.x;
    if (i8 >= (long)M * 32) return;
    long row = i8 >> 5;
    int c0 = ((int)(i8 & 31)) * 8;
    short8 v = *(const short8*)(tmp + row * D + c0);
    float r[8];
#pragma unroll
    for (int j = 0; j < 8; j++) {
        float2 ab = bnab[c0 + j];
        float x = b2f((ushort)v[j]);
        r[j] = fmaxf(ab.x * x + ab.y, 0.f);
    }
    if (last) {
        float4 f0 = make_float4(r[0], r[1], r[2], r[3]);
        float4 f1 = make_float4(r[4], r[5], r[6], r[7]);
        ((float4*)(out + row * D + c0))[0] = f0;
        ((float4*)(out + row * D + c0))[1] = f1;
    } else {
        float sc = invO[row];
        ushort w[8];
#pragma unroll
        for (int j = 0; j < 8; j++) { r[j] *= sc; w[j] = f2b(r[j]); }
        *(short8*)(Xout + row * D + c0) = *(short8*)w;       // bf16 hs for GEMM
        *(uint2*)(X8out + i8 * 2) = pk_fp8x8(r);             // fp8 hs for gather
    }
}

// ---------------- launch ----------------

extern "C" void kernel_launch(void* const* d_in, const int* in_sizes, int n_in,
                              void* d_out, int out_size, void* d_ws, size_t ws_size,
                              hipStream_t stream) {
    const float* x     = (const float*)d_in[0];
    const float* W     = (const float*)d_in[1];
    const float* b     = (const float*)d_in[2];
    const float* Wl    = (const float*)d_in[3];
    const float* bl    = (const float*)d_in[4];
    const float* gamma = (const float*)d_in[5];
    const float* beta  = (const float*)d_in[6];
    const int*   src   = (const int*)d_in[7];
    const int*   dst   = (const int*)d_in[8];

    const int N = in_sizes[0] / D;
    const int E = in_sizes[7];
    const int L = in_sizes[1] / (D * D);
    const int M_pad = (N + 1 + 127) & ~127;
    const int E_pad = E + 7 * N + 64;
    const int NBK = (N + 255) >> 8;
    float* out = (float*)d_out;

    char* p = (char*)d_ws;
    auto alloc = [&](size_t bytes) -> char* {
        char* r = p;
        p += (bytes + 255) & ~(size_t)255;
        return r;
    };
    int*      cur   = (int*)alloc((size_t)NBKMAX * 4);
    int*      cntO  = (int*)alloc((size_t)N * 4);
    int*      cntI  = (int*)alloc((size_t)N * 4);
    float*    invO  = (float*)alloc((size_t)(N + 1) * 4);
    float*    invOI = (float*)alloc((size_t)(N + 1) * 4);
    float*    sqrtO = (float*)alloc((size_t)(N + 1) * 4);
    int*      off_  = (int*)alloc((size_t)(N + 1) * 4);
    int*      bsum  = (int*)alloc(1024 * 4);
    int*      srcS  = (int*)alloc((size_t)E_pad * 4);
    ushort*   Wt    = (ushort*)alloc((size_t)L * 256 * 512 * 2);
    float*    bcat  = (float*)alloc((size_t)L * 256 * 4);
    ushort*   X     = (ushort*)alloc((size_t)M_pad * D * 2);     // hs bf16 (GEMM operand)
    unsigned* X8    = (unsigned*)alloc((size_t)M_pad * 64 * 4);  // hs fp8 (gather copy)
    ushort*   tmp   = (ushort*)alloc((size_t)M_pad * D * 2);     // pre-BN activations
    float*    bnsum = (float*)alloc((size_t)2 * D * 4);
    float*    bnsq  = bnsum + D;
    float2*   bnab  = (float2*)alloc((size_t)D * 8);

    unsigned* P     = (unsigned*)tmp;   // hist partials (32 MB), aliased (tmp dead until aggemm)
    unsigned* pairs = (unsigned*)tmp;   // bucketed pairs (13 MB), aliased

    {
        dim3 hg(HB, 8);
        hist_kernel<<<hg, 256, 0, stream>>>(src, dst, P, E);
        histreduce_kernel<<<512, 256, 0, stream>>>(P, cntO, cntI, N);
    }
    invsqrt_kernel<<<(N + 255) / 256, 256, 0, stream>>>(cntO, cntI, invO, invOI, sqrtO, N);
    int NB = (N + 1023) / 1024;
    scan1_kernel<<<NB, 256, 0, stream>>>(cntI, off_, bsum, N);
    scan2_kernel<<<1, 256, 0, stream>>>(bsum, NB);
    scan3_kernel<<<(N + 256) / 256, 256, 0, stream>>>(off_, bsum, cur, N);
    partA_kernel<<<512, 256, 0, stream>>>(src, dst, cur, pairs, E, NBK);
    partB_kernel<<<NBK, 256, 0, stream>>>(pairs, off_, cur, srcS, N);
    init_pad_kernel<<<1, 256, 0, stream>>>(X, X8, N);

    prep_w_kernel<<<(L * 256 * 512 + 255) / 256, 256, 0, stream>>>(W, Wl, b, bl, Wt, bcat, L);
    x2b_kernel<<<(int)(((long)N * 32 + 255) / 256), 256, 0, stream>>>(x, invO, X, X8, (long)N * 32);
    hipMemsetAsync(bnsum, 0, 2 * D * sizeof(float), stream);

    const int MB64 = (N + 63) / 64;
    const float invM = 1.0f / (float)N;
    for (int l = 0; l < L; l++) {
        int last = (l == L - 1);

        aggemm_kernel<<<MB64, 512, 0, stream>>>(X8, X, invOI, sqrtO, off_, srcS,
                                                Wt + (size_t)l * 256 * 512, bcat + l * 256,
                                                tmp, bnsum, bnsq, N);

        bnfin_kernel<<<1, 256, 0, stream>>>(bnsum, bnsq, gamma + l * D, beta + l * D, bnab, invM);
        bnrelu_kernel<<<(int)(((long)N * 32 + 255) / 256), 256, 0, stream>>>(
            tmp, bnab, invO, X, X8, out, N, last);
    }
}

// Round 18
// 758.429 us; speedup vs baseline: 1.1483x; 1.1483x over previous
//
#include <hip/hip_runtime.h>

#define D 256
#define BN_EPS 1e-5f

typedef __attribute__((ext_vector_type(8))) short short8;
typedef __attribute__((ext_vector_type(4))) float f32x4;
typedef __attribute__((ext_vector_type(2))) float f32x2;

__device__ __forceinline__ float b2f(ushort u) {
    union { unsigned u; float f; } c; c.u = ((unsigned)u) << 16; return c.f;
}
__device__ __forceinline__ ushort f2b(float f) {
    union { float f; unsigned u; } c; c.f = f;
    return (ushort)((c.u + 0x7fffu + ((c.u >> 16) & 1u)) >> 16);
}

typedef __attribute__((address_space(1))) const void gv_t;
typedef __attribute__((address_space(3))) void lv_t;
__device__ __forceinline__ void gld16(const void* g, void* l) {
    __builtin_amdgcn_global_load_lds((gv_t*)g, (lv_t*)l, 16, 0, 0);
}

// pack 8 floats -> 8 fp8 e4m3 (two dwords)
__device__ __forceinline__ uint2 pk_fp8x8(const float* r) {
    unsigned w0 = 0, w1 = 0;
    w0 = __builtin_amdgcn_cvt_pk_fp8_f32(r[0], r[1], w0, false);
    w0 = __builtin_amdgcn_cvt_pk_fp8_f32(r[2], r[3], w0, true);
    w1 = __builtin_amdgcn_cvt_pk_fp8_f32(r[4], r[5], w1, false);
    w1 = __builtin_amdgcn_cvt_pk_fp8_f32(r[6], r[7], w1, true);
    return make_uint2(w0, w1);
}

// ---------------- degree via LDS multi-range histogram ----------------

#define HB 64   // blocks per combo

__global__ __launch_bounds__(256) void hist_kernel(const int* __restrict__ src,
                                                   const int* __restrict__ dst,
                                                   unsigned* __restrict__ P, int E) {
    __shared__ unsigned lhist[16384];
    int combo = blockIdx.y;
    const int* arr = (combo >> 2) ? dst : src;
    unsigned base = (unsigned)(combo & 3) << 15;
    for (int j = threadIdx.x; j < 16384; j += 256) lhist[j] = 0;
    __syncthreads();
    int i0 = (blockIdx.x * 256 + threadIdx.x) * 4;
    int stride = HB * 256 * 4;
    for (int i = i0; i < E; i += stride) {
        if (i + 3 < E) {
            int4 v = *(const int4*)(arr + i);
            unsigned r0 = (unsigned)v.x - base;
            unsigned r1 = (unsigned)v.y - base;
            unsigned r2 = (unsigned)v.z - base;
            unsigned r3 = (unsigned)v.w - base;
            if (r0 < 32768u) atomicAdd(&lhist[r0 >> 1], 1u << ((r0 & 1) << 4));
            if (r1 < 32768u) atomicAdd(&lhist[r1 >> 1], 1u << ((r1 & 1) << 4));
            if (r2 < 32768u) atomicAdd(&lhist[r2 >> 1], 1u << ((r2 & 1) << 4));
            if (r3 < 32768u) atomicAdd(&lhist[r3 >> 1], 1u << ((r3 & 1) << 4));
        } else {
            for (int j = i; j < E; j++) {
                unsigned r = (unsigned)arr[j] - base;
                if (r < 32768u) atomicAdd(&lhist[r >> 1], 1u << ((r & 1) << 4));
            }
        }
    }
    __syncthreads();
    unsigned* dstp = P + ((size_t)(combo * HB + blockIdx.x) << 14);
    for (int j = threadIdx.x; j < 16384; j += 256) dstp[j] = lhist[j];
}

__global__ void histreduce_kernel(const unsigned* __restrict__ P,
                                  int* __restrict__ cntO, int* __restrict__ cntI, int N) {
    int g = blockIdx.x * 256 + threadIdx.x;       // 0 .. 131071
    int array = g >> 16;
    int p = g & 65535;
    int range = p >> 14;
    int j = p & 16383;
    const unsigned* Pp = P + ((size_t)((array * 4 + range) * HB) << 14) + j;
    unsigned s = 0;
#pragma unroll 8
    for (int b = 0; b < HB; b++) s += Pp[(size_t)b << 14];
    int bin = (range << 15) + 2 * j;
    int* cnt = array ? cntI : cntO;
    if (bin < N)     cnt[bin]     = (int)(s & 0xFFFFu);
    if (bin + 1 < N) cnt[bin + 1] = (int)(s >> 16);
}

__global__ void invsqrt_kernel(const int* __restrict__ cntO, const int* __restrict__ cntI,
                               float* __restrict__ invO, float* __restrict__ invOI,
                               float* __restrict__ sqrtO, int N) {
    int i = blockIdx.x * blockDim.x + threadIdx.x;
    if (i < N) {
        float dO = (float)max(cntO[i], 1);
        float io = rsqrtf(dO);
        invO[i] = io;
        sqrtO[i] = sqrtf(dO);
        invOI[i] = io * rsqrtf((float)max(cntI[i], 1));
    }
}

// hierarchical exclusive scan over PADDED counts ((deg+7)&~7)
__global__ void scan1_kernel(const int* __restrict__ cnt, int* __restrict__ off,
                             int* __restrict__ bsum, int n) {
    __shared__ int s[256];
    int t = threadIdx.x;
    int i0 = blockIdx.x * 1024 + t * 4;
    int v0 = (i0 < n) ? ((cnt[i0] + 7) & ~7) : 0;
    int v1 = (i0 + 1 < n) ? ((cnt[i0 + 1] + 7) & ~7) : 0;
    int v2 = (i0 + 2 < n) ? ((cnt[i0 + 2] + 7) & ~7) : 0;
    int v3 = (i0 + 3 < n) ? ((cnt[i0 + 3] + 7) & ~7) : 0;
    int tsum = v0 + v1 + v2 + v3;
    s[t] = tsum;
    __syncthreads();
    for (int d = 1; d < 256; d <<= 1) {
        int x = (t >= d) ? s[t - d] : 0;
        __syncthreads();
        s[t] += x;
        __syncthreads();
    }
    int excl = s[t] - tsum;
    if (i0 < n)     off[i0]     = excl;
    if (i0 + 1 < n) off[i0 + 1] = excl + v0;
    if (i0 + 2 < n) off[i0 + 2] = excl + v0 + v1;
    if (i0 + 3 < n) off[i0 + 3] = excl + v0 + v1 + v2;
    if (t == 255) bsum[blockIdx.x] = s[255];
}

__global__ void scan2_kernel(int* __restrict__ bsum, int nb) {
    __shared__ int s[256];
    int t = threadIdx.x;
    int v = (t < nb) ? bsum[t] : 0;
    s[t] = v;
    __syncthreads();
    for (int d = 1; d < 256; d <<= 1) {
        int x = (t >= d) ? s[t - d] : 0;
        __syncthreads();
        s[t] += x;
        __syncthreads();
    }
    if (t < nb) bsum[t] = s[t] - v;   // exclusive
    if (t == nb - 1) bsum[1023] = s[t];  // padded grand total
}

__global__ void scan3_kernel(int* __restrict__ off, const int* __restrict__ bsum,
                             int* __restrict__ bucketCur, int n) {
    int i = blockIdx.x * blockDim.x + threadIdx.x;
    if (i < n) {
        int v = off[i] + bsum[i >> 10];
        off[i] = v;
        if ((i & 255) == 0) bucketCur[i >> 8] = v;   // bucket cursor init fused
    } else if (i == n) {
        off[n] = bsum[1023];
    }
}

// ---------------- bucketed edge sort ----------------

#define NBKMAX 512

__global__ __launch_bounds__(256) void partA_kernel(const int* __restrict__ src,
                                                    const int* __restrict__ dst,
                                                    int* __restrict__ bucketCur,
                                                    unsigned* __restrict__ pairs,
                                                    int E, int NBK) {
    __shared__ int cnt[NBKMAX];
    __shared__ int base_s[NBKMAX];
    for (int j = threadIdx.x; j < NBK; j += 256) cnt[j] = 0;
    __syncthreads();
    for (int i = blockIdx.x * 256 + threadIdx.x; i < E; i += gridDim.x * 256)
        atomicAdd(&cnt[((unsigned)dst[i]) >> 8], 1);
    __syncthreads();
    for (int j = threadIdx.x; j < NBK; j += 256) {
        base_s[j] = atomicAdd(&bucketCur[j], cnt[j]);
        cnt[j] = 0;
    }
    __syncthreads();
    for (int i = blockIdx.x * 256 + threadIdx.x; i < E; i += gridDim.x * 256) {
        unsigned d = (unsigned)dst[i];
        unsigned b = d >> 8;
        int pos = base_s[b] + atomicAdd(&cnt[b], 1);
        pairs[pos] = ((unsigned)src[i] << 8) | (d & 255u);
    }
}

#define BCAP 14336

__global__ __launch_bounds__(256) void partB_kernel(const unsigned* __restrict__ pairs,
                                                    const int* __restrict__ off,
                                                    const int* __restrict__ bucketCur,
                                                    int* __restrict__ srcS, int N) {
    __shared__ int curL[256];
    __shared__ int stage[BCAP];
    int b = blockIdx.x;
    int n0 = b << 8;
    int n1 = min(n0 + 256, N);
    int base = off[n0];
    int len = off[n1] - base;
    if (len > BCAP) len = BCAP;
    for (int j = threadIdx.x; j < len; j += 256) stage[j] = N;
    int nn = n1 - n0;
    for (int i = threadIdx.x; i < nn; i += 256) curL[i] = off[n0 + i] - base;
    __syncthreads();
    int cntB = bucketCur[b] - base;
    for (int j = threadIdx.x; j < cntB; j += 256) {
        unsigned p = pairs[base + j];
        int pos = atomicAdd(&curL[p & 255u], 1);
        if (pos < BCAP) stage[pos] = (int)(p >> 8);
    }
    __syncthreads();
    for (int j4 = threadIdx.x; j4 * 4 < len; j4 += 256)
        *(int4*)(srcS + base + j4 * 4) = *(const int4*)(stage + j4 * 4);
}

// zero the dummy row N of X (bf16) and both halves of X8 (fp8, column-blocked)
__global__ void init_pad_kernel(ushort* __restrict__ X, unsigned* __restrict__ X8,
                                int N, long strideH) {
    int t = threadIdx.x;
    X[(size_t)N * D + t] = 0;
    if (t < 64) X8[(t >> 5) * strideH + (size_t)N * 32 + (t & 31)] = 0;
}

// ---------------- prep: Wt[l][n][k] = bf16 of [W; Wl+I]^T, bcat = b+bl ----------------

__global__ void prep_w_kernel(const float* __restrict__ W, const float* __restrict__ Wl,
                              const float* __restrict__ b, const float* __restrict__ bl,
                              ushort* __restrict__ Wt, float* __restrict__ bcat, int L) {
    int idx = blockIdx.x * blockDim.x + threadIdx.x;
    int k = idx & 511;
    int n = (idx >> 9) & 255;
    int l = idx >> 17;
    if (l >= L) return;
    float v;
    if (k < 256) {
        v = W[(size_t)l * 65536 + k * 256 + n];
    } else {
        v = Wl[(size_t)l * 65536 + (k - 256) * 256 + n];
        if (k - 256 == n) v += 1.0f;      // residual folded: h@Wl + h = h@(Wl+I)
    }
    Wt[idx] = f2b(v);
    if (k == 0) bcat[l * 256 + n] = b[l * 256 + n] + bl[l * 256 + n];
}

// x -> hs0 = x * invO[row]: bf16 copy (GEMM) + column-blocked fp8 copy (gather)
__global__ void x2b_kernel(const float* __restrict__ x, const float* __restrict__ invO,
                           ushort* __restrict__ hs, unsigned* __restrict__ hs8,
                           long strideH, long n8) {
    long i8 = (long)blockIdx.x * blockDim.x + threadIdx.x;
    if (i8 >= n8) return;
    long row = i8 >> 5;
    float sc = invO[row];
    float4 a = ((const float4*)x)[i8 * 2];
    float4 b = ((const float4*)x)[i8 * 2 + 1];
    float r[8] = { a.x * sc, a.y * sc, a.z * sc, a.w * sc,
                   b.x * sc, b.y * sc, b.z * sc, b.w * sc };
    ushort v[8];
#pragma unroll
    for (int j = 0; j < 8; j++) v[j] = f2b(r[j]);
    *(short8*)(hs + i8 * 8) = *(short8*)v;
    long H = (i8 >> 4) & 1;
    *(uint2*)(hs8 + H * strideH + row * 32 + (i8 & 15) * 2) = pk_fp8x8(r);
}

// ---------------- per-layer: feature-split aggregate (both halves, one dispatch) ----------------

__global__ void aggregate_kernel(const unsigned* __restrict__ X8,
                                 const float* __restrict__ invOI,
                                 const int* __restrict__ off, const int* __restrict__ srcS,
                                 ushort* __restrict__ aggs, long strideH, int N) {
    const unsigned* hs8h = X8 + blockIdx.y * strideH;
    ushort* aggsh = aggs + blockIdx.y * 128;
    int tid = threadIdx.x;
    int wid = tid >> 6, lane = tid & 63;
    int l32 = lane & 31;
    int node = blockIdx.x * 8 + wid * 2 + (lane >> 5);
    if (blockIdx.x * 8 + wid * 2 >= N) return;
    bool valid = node < N;
    int e0 = valid ? off[node] : 0;
    int e1 = valid ? off[node + 1] : 0;
    f32x2 A01 = {0.f, 0.f}, A23 = {0.f, 0.f};
    for (int e = e0; e < e1; e += 8) {
        int4 c0 = *(const int4*)(srcS + e);
        int4 c1 = *(const int4*)(srcS + e + 4);
        unsigned g0 = hs8h[(size_t)c0.x * 32 + l32];
        unsigned g1 = hs8h[(size_t)c0.y * 32 + l32];
        unsigned g2 = hs8h[(size_t)c0.z * 32 + l32];
        unsigned g3 = hs8h[(size_t)c0.w * 32 + l32];
        unsigned g4 = hs8h[(size_t)c1.x * 32 + l32];
        unsigned g5 = hs8h[(size_t)c1.y * 32 + l32];
        unsigned g6 = hs8h[(size_t)c1.z * 32 + l32];
        unsigned g7 = hs8h[(size_t)c1.w * 32 + l32];
#pragma unroll
        for (int q = 0; q < 8; q++) {
            unsigned g = (q == 0) ? g0 : (q == 1) ? g1 : (q == 2) ? g2 : (q == 3) ? g3
                       : (q == 4) ? g4 : (q == 5) ? g5 : (q == 6) ? g6 : g7;
            A01 += __builtin_amdgcn_cvt_pk_f32_fp8(g, false);
            A23 += __builtin_amdgcn_cvt_pk_f32_fp8(g, true);
        }
    }
    if (valid) {
        float wi = invOI[node];
        ushort4 o;
        o.x = f2b(A01[0] * wi); o.y = f2b(A01[1] * wi);
        o.z = f2b(A23[0] * wi); o.w = f2b(A23[1] * wi);
        *(ushort4*)(aggsh + (size_t)node * D + l32 * 4) = o;
    }
}

// ---------------- fused MFMA GEMM: 128x256 tile, 8 waves, single-buffer, 4 blocks/CU ----------------
// LDS 24 KB (A 8 KB + B 16 KB); launch_bounds(512,4) caps VGPR at 128 (compiler uses ~64,
// NO spill -- the (512,8) variant forced VGPR=32 and spilled acc to scratch, 5x regression).
// 4 blocks/CU (thread-capped): all 782 blocks co-resident, zero dispatch tail.

#define BSOFF 4096   // shorts

__global__ __launch_bounds__(512, 4) void gemm_kernel(
        const ushort* __restrict__ aggs, const ushort* __restrict__ hs,
        const ushort* __restrict__ Wt,  const float* __restrict__ bcat,
        const float* __restrict__ sqrtO,
        ushort* __restrict__ tmp, float* __restrict__ bnsum, float* __restrict__ bnsq,
        int M) {
    __shared__ short SH[12288];   // 24 KB

    int bm0 = blockIdx.x * 128;
    if (bm0 >= M) return;

    int tid = threadIdx.x;
    int wid = tid >> 6, lane = tid & 63;
    int wr = wid >> 2, wc = wid & 3;          // wave grid 2 (rows) x 4 (cols)
    int lrow = lane & 15, lkh = lane >> 4;
    int srow = lane >> 2;
    int sseg = (lane & 3) ^ ((srow >> 1) & 3);

    f32x4 acc[4][4] = {};

#pragma unroll
    for (int k0 = 0; k0 < 512; k0 += 32) {
        {
            int kk_ = k0 & 255;
            const ushort* Ah_ = (k0 < 256) ? aggs : hs;
            gld16(Ah_ + (size_t)(bm0 + wid * 16 + srow) * 256 + kk_ + sseg * 8,
                  SH + (wid * 16) * 32);
            const ushort* gb_ = Wt + (size_t)(wid * 32 + srow) * 512 + k0 + sseg * 8;
            gld16(gb_,            SH + BSOFF + (wid * 32) * 32);
            gld16(gb_ + 16 * 512, SH + BSOFF + (wid * 32 + 16) * 32);
        }
        __syncthreads();

        short8 a[4], bfr[4];
#pragma unroll
        for (int m = 0; m < 4; m++) {
            int ra = wr * 64 + m * 16 + lrow;
            a[m] = *(short8*)&SH[ra * 32 + (lkh ^ ((ra >> 1) & 3)) * 8];
        }
#pragma unroll
        for (int n = 0; n < 4; n++) {
            int rb = wc * 64 + n * 16 + lrow;
            bfr[n] = *(short8*)&SH[BSOFF + rb * 32 + (lkh ^ ((rb >> 1) & 3)) * 8];
        }
#pragma unroll
        for (int m = 0; m < 4; m++)
#pragma unroll
            for (int n = 0; n < 4; n++)
                acc[m][n] = __builtin_amdgcn_mfma_f32_16x16x32_bf16(a[m], bfr[n], acc[m][n], 0, 0, 0);
        __syncthreads();
    }

    // register phase: scale rows, bias, bf16 values, column stats
    ushort outv[4][4][4];
#pragma unroll
    for (int n = 0; n < 4; n++) {
        int col = wc * 64 + n * 16 + lrow;
        float bc = bcat[col];
        float s_part = 0.f, q_part = 0.f;
#pragma unroll
        for (int m = 0; m < 4; m++) {
            int rbase = bm0 + wr * 64 + m * 16 + lkh * 4;
#pragma unroll
            for (int i = 0; i < 4; i++) {
                int row = rbase + i;
                float v = (row < M) ? (acc[m][n][i] * sqrtO[row] + bc) : 0.f;
                outv[m][n][i] = f2b(v);
                if (row < M) { s_part += v; q_part += v * v; }
            }
        }
        s_part += __shfl_xor(s_part, 16);
        s_part += __shfl_xor(s_part, 32);
        q_part += __shfl_xor(q_part, 16);
        q_part += __shfl_xor(q_part, 32);
        if (lkh == 0) {
            atomicAdd(&bnsum[col], s_part);
            atomicAdd(&bnsq[col], q_part);
        }
    }

    // coalesced store via LDS: four 32x256 quarter-tiles (16 KB each, fits in SH)
#pragma unroll
    for (int q = 0; q < 4; q++) {
        __syncthreads();
        if (wr == (q >> 1)) {
#pragma unroll
            for (int mm = 0; mm < 2; mm++) {
                int m = (q & 1) * 2 + mm;
#pragma unroll
                for (int n = 0; n < 4; n++)
#pragma unroll
                    for (int i = 0; i < 4; i++)
                        SH[(mm * 16 + lkh * 4 + i) * 256 + wc * 64 + n * 16 + lrow] =
                            (short)outv[m][n][i];
            }
        }
        __syncthreads();
        int rl = tid >> 4;
        int c0 = (tid & 15) * 16;
        int row = bm0 + q * 32 + rl;
        if (row < M) {
            *(short8*)(tmp + (size_t)row * 256 + c0)     = *(short8*)&SH[rl * 256 + c0];
            *(short8*)(tmp + (size_t)row * 256 + c0 + 8) = *(short8*)&SH[rl * 256 + c0 + 8];
        }
    }
}

// ---------------- BN finalize (+ re-zero stats for next layer) ----------------

__global__ void bnfin_kernel(float* __restrict__ bnsum, float* __restrict__ bnsq,
                             const float* __restrict__ gamma, const float* __restrict__ beta,
                             float2* __restrict__ bnab, float invM) {
    int c = threadIdx.x;
    float mean = bnsum[c] * invM;
    float var = bnsq[c] * invM - mean * mean;
    float a = gamma[c] * rsqrtf(var + BN_EPS);
    bnab[c] = make_float2(a, beta[c] - a * mean);
    bnsum[c] = 0.f;
    bnsq[c] = 0.f;
}

__global__ void bnrelu_kernel(const ushort* __restrict__ tmp, const float2* __restrict__ bnab,
                              const float* __restrict__ invO, ushort* __restrict__ Xout,
                              unsigned* __restrict__ X8out, long strideH,
                              float* __restrict__ out, int M, int last) {
    long i8 = (long)blockIdx.x * blockDim.x + threadIdx.x;
    if (i8 >= (long)M * 32) return;
    long row = i8 >> 5;
    int c0 = ((int)(i8 & 31)) * 8;
    short8 v = *(const short8*)(tmp + row * D + c0);
    float r[8];
#pragma unroll
    for (int j = 0; j < 8; j++) {
        float2 ab = bnab[c0 + j];
        float x = b2f((ushort)v[j]);
        r[j] = fmaxf(ab.x * x + ab.y, 0.f);
    }
    if (last) {
        float4 f0 = make_float4(r[0], r[1], r[2], r[3]);
        float4 f1 = make_float4(r[4], r[5], r[6], r[7]);
        ((float4*)(out + row * D + c0))[0] = f0;
        ((float4*)(out + row * D + c0))[1] = f1;
    } else {
        float sc = invO[row];
        ushort w[8];
#pragma unroll
        for (int j = 0; j < 8; j++) { r[j] *= sc; w[j] = f2b(r[j]); }
        *(short8*)(Xout + row * D + c0) = *(short8*)w;       // bf16 hs for GEMM
        long H = (i8 >> 4) & 1;
        *(uint2*)(X8out + H * strideH + row * 32 + (i8 & 15) * 2) = pk_fp8x8(r);
    }
}

// ---------------- launch ----------------

extern "C" void kernel_launch(void* const* d_in, const int* in_sizes, int n_in,
                              void* d_out, int out_size, void* d_ws, size_t ws_size,
                              hipStream_t stream) {
    const float* x     = (const float*)d_in[0];
    const float* W     = (const float*)d_in[1];
    const float* b     = (const float*)d_in[2];
    const float* Wl    = (const float*)d_in[3];
    const float* bl    = (const float*)d_in[4];
    const float* gamma = (const float*)d_in[5];
    const float* beta  = (const float*)d_in[6];
    const int*   src   = (const int*)d_in[7];
    const int*   dst   = (const int*)d_in[8];

    const int N = in_sizes[0] / D;
    const int E = in_sizes[7];
    const int L = in_sizes[1] / (D * D);
    const int M_pad = (N + 1 + 127) & ~127;
    const int E_pad = E + 7 * N + 64;
    const int NBK = (N + 255) >> 8;
    const long strideH = (long)M_pad * 32;   // dwords per fp8 feature-half
    float* out = (float*)d_out;

    char* p = (char*)d_ws;
    auto alloc = [&](size_t bytes) -> char* {
        char* r = p;
        p += (bytes + 255) & ~(size_t)255;
        return r;
    };
    int*      cur   = (int*)alloc((size_t)NBKMAX * 4);
    int*      cntO  = (int*)alloc((size_t)N * 4);
    int*      cntI  = (int*)alloc((size_t)N * 4);
    float*    invO  = (float*)alloc((size_t)(N + 1) * 4);
    float*    invOI = (float*)alloc((size_t)(N + 1) * 4);
    float*    sqrtO = (float*)alloc((size_t)(N + 1) * 4);
    int*      off_  = (int*)alloc((size_t)(N + 1) * 4);
    int*      bsum  = (int*)alloc(1024 * 4);
    int*      srcS  = (int*)alloc((size_t)E_pad * 4);
    ushort*   Wt    = (ushort*)alloc((size_t)L * 256 * 512 * 2);
    float*    bcat  = (float*)alloc((size_t)L * 256 * 4);
    ushort*   X     = (ushort*)alloc((size_t)M_pad * D * 2);     // hs bf16 (GEMM operand)
    unsigned* X8    = (unsigned*)alloc((size_t)2 * strideH * 4); // hs fp8, column-blocked halves
    ushort*   aggs  = (ushort*)alloc((size_t)M_pad * D * 2);     // scaled aggregate
    ushort*   tmp   = (ushort*)alloc((size_t)M_pad * D * 2);     // pre-BN activations
    float*    bnsum = (float*)alloc((size_t)2 * D * 4);
    float*    bnsq  = bnsum + D;
    float2*   bnab  = (float2*)alloc((size_t)D * 8);

    unsigned* P     = (unsigned*)aggs;   // hist partials (32 MB), aliased (dead until aggregate)
    unsigned* pairs = (unsigned*)aggs;   // bucketed pairs (13 MB), aliased

    {
        dim3 hg(HB, 8);
        hist_kernel<<<hg, 256, 0, stream>>>(src, dst, P, E);
        histreduce_kernel<<<512, 256, 0, stream>>>(P, cntO, cntI, N);
    }
    invsqrt_kernel<<<(N + 255) / 256, 256, 0, stream>>>(cntO, cntI, invO, invOI, sqrtO, N);
    int NB = (N + 1023) / 1024;
    scan1_kernel<<<NB, 256, 0, stream>>>(cntI, off_, bsum, N);
    scan2_kernel<<<1, 256, 0, stream>>>(bsum, NB);
    scan3_kernel<<<(N + 256) / 256, 256, 0, stream>>>(off_, bsum, cur, N);
    partA_kernel<<<512, 256, 0, stream>>>(src, dst, cur, pairs, E, NBK);
    partB_kernel<<<NBK, 256, 0, stream>>>(pairs, off_, cur, srcS, N);
    init_pad_kernel<<<1, 256, 0, stream>>>(X, X8, N, strideH);

    prep_w_kernel<<<(L * 256 * 512 + 255) / 256, 256, 0, stream>>>(W, Wl, b, bl, Wt, bcat, L);
    x2b_kernel<<<(int)(((long)N * 32 + 255) / 256), 256, 0, stream>>>(
        x, invO, X, X8, strideH, (long)N * 32);
    hipMemsetAsync(bnsum, 0, 2 * D * sizeof(float), stream);

    const int MB = (N + 127) / 128;
    const dim3 ag((N + 7) / 8, 2);
    const float invM = 1.0f / (float)N;
    for (int l = 0; l < L; l++) {
        int last = (l == L - 1);

        aggregate_kernel<<<ag, 256, 0, stream>>>(X8, invOI, off_, srcS, aggs, strideH, N);

        gemm_kernel<<<MB, 512, 0, stream>>>(aggs, X, Wt + (size_t)l * 256 * 512,
                                            bcat + l * 256, sqrtO, tmp, bnsum, bnsq, N);

        bnfin_kernel<<<1, 256, 0, stream>>>(bnsum, bnsq, gamma + l * D, beta + l * D, bnab, invM);
        bnrelu_kernel<<<(int)(((long)N * 32 + 255) / 256), 256, 0, stream>>>(
            tmp, bnab, invO, X, X8, strideH, out, N, last);
    }
}